// Round 11
// baseline (2131.861 us; speedup 1.0000x reference)
//
#include <hip/hip_runtime.h>
#include <cmath>

// Problem constants
constexpr int kN   = 4096;
constexpr int kIN  = 3000;
constexpr int kINp = 3072;   // kIN padded to 128-multiple
constexpr int kLAT = 64;

enum { SL = 0, FEAT, ALN, FXA, FXB, SM1, SM2, SPS, NSLOT };

typedef __bf16 bf16x8 __attribute__((ext_vector_type(8)));
typedef float f32x4 __attribute__((ext_vector_type(4)));
typedef unsigned short u16x8 __attribute__((ext_vector_type(8)));
typedef unsigned short u16x4 __attribute__((ext_vector_type(4)));

// ---------------- reduction helpers ----------------
template<bool IS_MAX>
__device__ __forceinline__ float blk_red(float v) {
  __shared__ float buf[8];
  #pragma unroll
  for (int s = 32; s > 0; s >>= 1) {
    float o = __shfl_down(v, s, 64);
    v = IS_MAX ? fmaxf(v, o) : (v + o);
  }
  int lane = threadIdx.x & 63, wv = threadIdx.x >> 6, nw = blockDim.x >> 6;
  __syncthreads();
  if (lane == 0) buf[wv] = v;
  __syncthreads();
  float r = buf[0];
  for (int i = 1; i < nw; i++) r = IS_MAX ? fmaxf(r, buf[i]) : (r + buf[i]);
  __syncthreads();
  return r;
}

__device__ __forceinline__ float wave_red_sum(float v) {
  #pragma unroll
  for (int s = 32; s > 0; s >>= 1) v += __shfl_down(v, s, 64);
  return v;
}

// fp32 -> bf16 RNE ; bf16 -> fp32
__device__ __forceinline__ unsigned short f2bf(float f) {
  unsigned u = __builtin_bit_cast(unsigned, f);
  u += 0x7fffu + ((u >> 16) & 1u);
  return (unsigned short)(u >> 16);
}
__device__ __forceinline__ float bf2f(unsigned short h) {
  return __builtin_bit_cast(float, (unsigned)h << 16);
}

// async global->LDS, 16B per lane
__device__ __forceinline__ void gload16(const unsigned short* g, unsigned short* l) {
  __builtin_amdgcn_global_load_lds(
      (const __attribute__((address_space(1))) unsigned int*)g,
      (__attribute__((address_space(3))) unsigned int*)l, 16, 0, 0);
}

#define VMW(n) asm volatile("s_waitcnt vmcnt(" #n ")" ::: "memory")

// triangular decode: lu in [0,528) -> upper-tri tile (by,bx) of 32x32 grid
__device__ __forceinline__ void tri_decode(int lu, int& bx, int& by) {
  int x = lu & 7, i = lu >> 3;
  int u = x * 66 + i;
  float disc = 4225.f - 8.f * (float)u;
  by = (int)((65.f - sqrtf(fmaxf(disc, 0.f))) * 0.5f);
  while (by > 0 && 32 * by - by * (by - 1) / 2 > u) by--;
  while (32 * (by + 1) - (by + 1) * by / 2 <= u) by++;
  bx = by + (u - (32 * by - by * (by - 1) / 2));
}

// ================== 128-tile bf16 MFMA GEMM: C = A @ Bt^T ==================
// 3-deep pipeline, counted vmcnt. Dense strip decode (R9 proven).
// EPI 0: Cb = bf16(acc / rowdiv[r])
// EPI 1: Cf = acc (fp32)
// EPI 2: slot += sum (X - acc/rd/cd)^2 (X fp32 XBF=0 / bf16 XBF=1)
// EPI 3: align+sparsity epilogue
template<int EPI, int XBF>
__global__ __launch_bounds__(256)
void bt_mfma_k(const unsigned short* __restrict__ A, const unsigned short* __restrict__ Bt,
               unsigned short* __restrict__ Cb, float* __restrict__ Cf,
               const void* __restrict__ Xv,
               const float* __restrict__ rowdiv, const float* __restrict__ coldiv,
               float* __restrict__ slot, int gx, int Nc, int K, int ldX)
{
  __shared__ unsigned short AB[3 * 8192];

  int orig = blockIdx.x;
  int x = orig & 7, tt = orig >> 3;
  int bx = tt >> 2;
  int by = x * 4 + (tt & 3);
  const int row0 = by * 128, col0 = bx * 128;

  const int t = threadIdx.x, l = t & 63, wv = t >> 6;
  const int wr = wv >> 1, wc = wv & 1;
  const int lr = l & 15, lkh = (l >> 4) << 3;

  f32x4 acc[4][4];
  #pragma unroll
  for (int i = 0; i < 4; i++)
    #pragma unroll
    for (int j = 0; j < 4; j++) acc[i][j] = (f32x4){0.f, 0.f, 0.f, 0.f};

  const int srow = l >> 2;
  const int sk   = (l & 3) << 3;
  const unsigned short* Ab = A  + (size_t)(row0 + srow) * K + sk;
  const unsigned short* Bb = Bt + (size_t)(col0 + srow) * K + sk;

  const int NT = K >> 5;

  auto STAGE = [&](int kt, int buf) {
    unsigned short* As = AB + buf * 8192;
    unsigned short* Bs = As + 4096;
    int k0 = kt << 5;
    #pragma unroll
    for (int h2 = 0; h2 < 2; h2++) {
      int c = wv * 2 + h2;
      gload16(Ab + (size_t)c * 16 * K + k0, As + c * 512);
      gload16(Bb + (size_t)c * 16 * K + k0, Bs + c * 512);
    }
  };

  STAGE(0, 0);
  if (NT > 1) STAGE(1, 1);
  if (NT > 2) STAGE(2, 2);
  int cur = 0;

  for (int kt = 0; kt < NT; ++kt) {
    int ahead = NT - 1 - kt;
    if (ahead >= 2)      { VMW(8); }
    else if (ahead == 1) { VMW(4); }
    else                 { VMW(0); }
    __builtin_amdgcn_sched_barrier(0);
    __builtin_amdgcn_s_barrier();

    const unsigned short* As = AB + cur * 8192;
    const unsigned short* Bs = As + 4096;
    u16x8 af[4], bfv[4];
    #pragma unroll
    for (int mi = 0; mi < 4; mi++)
      af[mi] = *(const u16x8*)&As[(wr * 64 + mi * 16 + lr) * 32 + lkh];
    #pragma unroll
    for (int ni = 0; ni < 4; ni++)
      bfv[ni] = *(const u16x8*)&Bs[(wc * 64 + ni * 16 + lr) * 32 + lkh];
    #pragma unroll
    for (int mi = 0; mi < 4; mi++)
      #pragma unroll
      for (int ni = 0; ni < 4; ni++)
        acc[mi][ni] = __builtin_amdgcn_mfma_f32_16x16x32_bf16(
            __builtin_bit_cast(bf16x8, af[mi]),
            __builtin_bit_cast(bf16x8, bfv[ni]), acc[mi][ni], 0, 0, 0);

    __builtin_amdgcn_s_barrier();
    if (kt + 3 < NT) STAGE(kt + 3, cur);
    cur = (cur == 2) ? 0 : cur + 1;
  }

  const int lcol = l & 15, lrow = (l >> 4) << 2;
  if (EPI == 0) {
    #pragma unroll
    for (int mi = 0; mi < 4; mi++) {
      int rr = row0 + wr * 64 + mi * 16 + lrow;
      #pragma unroll
      for (int ni = 0; ni < 4; ni++) {
        int cc = col0 + wc * 64 + ni * 16 + lcol;
        #pragma unroll
        for (int r = 0; r < 4; r++) {
          float v = acc[mi][ni][r];
          if (rowdiv) v /= rowdiv[rr + r];
          Cb[(size_t)(rr + r) * 4096 + cc] = f2bf(v);
        }
      }
    }
  } else if (EPI == 1) {
    #pragma unroll
    for (int mi = 0; mi < 4; mi++) {
      int rr = row0 + wr * 64 + mi * 16 + lrow;
      #pragma unroll
      for (int ni = 0; ni < 4; ni++) {
        int cc = col0 + wc * 64 + ni * 16 + lcol;
        #pragma unroll
        for (int r = 0; r < 4; r++)
          Cf[(size_t)(rr + r) * 4096 + cc] = acc[mi][ni][r];
      }
    }
  } else if (EPI == 2) {
    const float* Xf = (const float*)Xv;
    const unsigned short* Xh = (const unsigned short*)Xv;
    float part = 0.f;
    #pragma unroll
    for (int mi = 0; mi < 4; mi++) {
      int rr = row0 + wr * 64 + mi * 16 + lrow;
      #pragma unroll
      for (int ni = 0; ni < 4; ni++) {
        int cc = col0 + wc * 64 + ni * 16 + lcol;
        if (cc < Nc) {
          float cd = coldiv ? coldiv[cc] : 1.f;
          #pragma unroll
          for (int r = 0; r < 4; r++) {
            float v = acc[mi][ni][r];
            if (rowdiv) v /= rowdiv[rr + r];
            v /= cd;
            size_t xi = (size_t)(rr + r) * ldX + cc;
            float xval = XBF ? bf2f(Xh[xi]) : Xf[xi];
            float d = xval - v;
            part = fmaf(d, d, part);
          }
        }
      }
    }
    part = blk_red<false>(part);
    if (t == 0) atomicAdd(slot, part);
  } else { // EPI 3
    const unsigned short* Ph = (const unsigned short*)Xv;
    float a = 0.f, sp = 0.f;
    #pragma unroll
    for (int mi = 0; mi < 4; mi++) {
      int rr = row0 + wr * 64 + mi * 16 + lrow;
      #pragma unroll
      for (int ni = 0; ni < 4; ni++) {
        int cc = col0 + wc * 64 + ni * 16 + lcol;
        #pragma unroll
        for (int r = 0; r < 4; r++) {
          float g = acc[mi][ni][r];
          float p = bf2f(Ph[(size_t)(rr + r) * ldX + cc]);
          float d2 = rowdiv[rr + r] + coldiv[cc] - 2.f * g;
          a = fmaf(p, sqrtf(fmaxf(d2, 1e-12f)), a);
          sp = fmaf(p, logf(p + 1e-10f), sp);
        }
      }
    }
    a = blk_red<false>(a);
    sp = blk_red<false>(sp);
    if (t == 0) { atomicAdd(&slot[ALN], a); atomicAdd(&slot[SPS], sp); }
  }
}

// ========== merged two-GEMM EPI2 reduce kernel (grid-stride tile loop) ==========
// Tiles u in [0,ntiles): set0 for u<split, set1 otherwise (local lu).
// SYM=1: triangular decode of lu (528 tiles/half, x2 off-diag weight).
// SYM=0: dense strip decode (gx cols x 32 row-tiles per half).
// slot += wgt * sum (X - acc/rowdiv[r]/coldiv[c])^2
template<int XBF, int SYM>
__global__ __launch_bounds__(256)
void bt2_mfma_k(const unsigned short* __restrict__ A0, const unsigned short* __restrict__ B0,
                const void* __restrict__ X0, const float* __restrict__ rd0,
                const float* __restrict__ cd0, float* __restrict__ slot0,
                const unsigned short* __restrict__ A1, const unsigned short* __restrict__ B1,
                const void* __restrict__ X1, const float* __restrict__ rd1,
                const float* __restrict__ cd1, float* __restrict__ slot1,
                int gx, int Nc, int K, int ldX, int ntiles, int split)
{
  __shared__ unsigned short AB[3 * 8192];
  const int t = threadIdx.x, l = t & 63, wv = t >> 6;
  const int wr = wv >> 1, wc = wv & 1;
  const int lr = l & 15, lkh = (l >> 4) << 3;
  const int srow = l >> 2;
  const int sk   = (l & 3) << 3;
  const int NT = K >> 5;

  for (int u = blockIdx.x; u < ntiles; u += gridDim.x) {
    const int s1 = (u >= split);
    const int lu = s1 ? (u - split) : u;
    const unsigned short* A  = s1 ? A1 : A0;
    const unsigned short* Bt = s1 ? B1 : B0;
    const void* Xv           = s1 ? X1 : X0;
    const float* rowdiv      = s1 ? rd1 : rd0;
    const float* coldiv      = s1 ? cd1 : cd0;
    float* slot              = s1 ? slot1 : slot0;

    int bx, by;
    if (SYM) {
      tri_decode(lu, bx, by);
    } else {
      int x = lu & 7, tt = lu >> 3;
      bx = tt >> 2;
      by = x * 4 + (tt & 3);
    }
    const int row0 = by * 128, col0 = bx * 128;

    f32x4 acc[4][4];
    #pragma unroll
    for (int i = 0; i < 4; i++)
      #pragma unroll
      for (int j = 0; j < 4; j++) acc[i][j] = (f32x4){0.f, 0.f, 0.f, 0.f};

    const unsigned short* Ab = A  + (size_t)(row0 + srow) * K + sk;
    const unsigned short* Bb = Bt + (size_t)(col0 + srow) * K + sk;

    auto STAGE = [&](int kt, int buf) {
      unsigned short* As = AB + buf * 8192;
      unsigned short* Bs = As + 4096;
      int k0 = kt << 5;
      #pragma unroll
      for (int h2 = 0; h2 < 2; h2++) {
        int c = wv * 2 + h2;
        gload16(Ab + (size_t)c * 16 * K + k0, As + c * 512);
        gload16(Bb + (size_t)c * 16 * K + k0, Bs + c * 512);
      }
    };

    STAGE(0, 0);
    if (NT > 1) STAGE(1, 1);
    if (NT > 2) STAGE(2, 2);
    int cur = 0;

    for (int kt = 0; kt < NT; ++kt) {
      int ahead = NT - 1 - kt;
      if (ahead >= 2)      { VMW(8); }
      else if (ahead == 1) { VMW(4); }
      else                 { VMW(0); }
      __builtin_amdgcn_sched_barrier(0);
      __builtin_amdgcn_s_barrier();

      const unsigned short* As = AB + cur * 8192;
      const unsigned short* Bs = As + 4096;
      u16x8 af[4], bfv[4];
      #pragma unroll
      for (int mi = 0; mi < 4; mi++)
        af[mi] = *(const u16x8*)&As[(wr * 64 + mi * 16 + lr) * 32 + lkh];
      #pragma unroll
      for (int ni = 0; ni < 4; ni++)
        bfv[ni] = *(const u16x8*)&Bs[(wc * 64 + ni * 16 + lr) * 32 + lkh];
      #pragma unroll
      for (int mi = 0; mi < 4; mi++)
        #pragma unroll
        for (int ni = 0; ni < 4; ni++)
          acc[mi][ni] = __builtin_amdgcn_mfma_f32_16x16x32_bf16(
              __builtin_bit_cast(bf16x8, af[mi]),
              __builtin_bit_cast(bf16x8, bfv[ni]), acc[mi][ni], 0, 0, 0);

      __builtin_amdgcn_s_barrier();
      if (kt + 3 < NT) STAGE(kt + 3, cur);
      cur = (cur == 2) ? 0 : cur + 1;
    }

    const int lcol = l & 15, lrow = (l >> 4) << 2;
    const float* Xf = (const float*)Xv;
    const unsigned short* Xh = (const unsigned short*)Xv;
    float part = 0.f;
    #pragma unroll
    for (int mi = 0; mi < 4; mi++) {
      int rr = row0 + wr * 64 + mi * 16 + lrow;
      #pragma unroll
      for (int ni = 0; ni < 4; ni++) {
        int cc = col0 + wc * 64 + ni * 16 + lcol;
        if (cc < Nc) {
          float cd = coldiv ? coldiv[cc] : 1.f;
          #pragma unroll
          for (int r = 0; r < 4; r++) {
            float v = acc[mi][ni][r];
            if (rowdiv) v /= rowdiv[rr + r];
            v /= cd;
            size_t xi = (size_t)(rr + r) * ldX + cc;
            float xval = XBF ? bf2f(Xh[xi]) : Xf[xi];
            float d = xval - v;
            part = fmaf(d, d, part);
          }
        }
      }
    }
    part = blk_red<false>(part);
    if (t == 0) {
      float wgt = (SYM && col0 > row0) ? 2.f : 1.f;
      atomicAdd(slot, part * wgt);
    }
    __syncthreads();   // all lanes done with AB + blk_red buf before next tile
  }
}

// ============ narrow split-K bf16 MFMA: C[4096][Nc<=128] += A @ Bt^T ============
__global__ __launch_bounds__(256)
void ns_mfma_k(const unsigned short* __restrict__ A, const unsigned short* __restrict__ Bt,
               float* __restrict__ C, int Nc, int K, int KC, int ldC)
{
  __shared__ unsigned short AB[2 * 8192];
  int ks = blockIdx.x & 15, strip = blockIdx.x >> 4;
  const int row0 = strip * 128;
  const int kbase = ks * KC;

  const int t = threadIdx.x, l = t & 63, wv = t >> 6;
  const int wr = wv >> 1, wc = wv & 1;
  const int lr = l & 15, lkh = (l >> 4) << 3;

  f32x4 acc[4][4];
  #pragma unroll
  for (int i = 0; i < 4; i++)
    #pragma unroll
    for (int j = 0; j < 4; j++) acc[i][j] = (f32x4){0.f, 0.f, 0.f, 0.f};

  const int srow = l >> 2;
  const int sk   = (l & 3) << 3;
  const unsigned short* Ab = A  + (size_t)(row0 + srow) * K + kbase + sk;
  const unsigned short* Bb = Bt + (size_t)srow * K + kbase + sk;

  const int NT = KC >> 5;

  auto STAGE = [&](int kt, int buf) {
    unsigned short* As = AB + buf * 8192;
    unsigned short* Bs = As + 4096;
    int k0 = kt << 5;
    #pragma unroll
    for (int h2 = 0; h2 < 2; h2++) {
      int c = wv * 2 + h2;
      gload16(Ab + (size_t)c * 16 * K + k0, As + c * 512);
      gload16(Bb + (size_t)c * 16 * K + k0, Bs + c * 512);
    }
  };

  STAGE(0, 0);
  if (NT > 1) STAGE(1, 1);
  int cur = 0;

  for (int kt = 0; kt < NT; ++kt) {
    if (kt + 1 < NT) { VMW(4); }
    else             { VMW(0); }
    __builtin_amdgcn_sched_barrier(0);
    __builtin_amdgcn_s_barrier();

    const unsigned short* As = AB + cur * 8192;
    const unsigned short* Bs = As + 4096;
    u16x8 af[4], bfv[4];
    #pragma unroll
    for (int mi = 0; mi < 4; mi++)
      af[mi] = *(const u16x8*)&As[(wr * 64 + mi * 16 + lr) * 32 + lkh];
    #pragma unroll
    for (int ni = 0; ni < 4; ni++)
      bfv[ni] = *(const u16x8*)&Bs[(wc * 64 + ni * 16 + lr) * 32 + lkh];
    #pragma unroll
    for (int mi = 0; mi < 4; mi++)
      #pragma unroll
      for (int ni = 0; ni < 4; ni++)
        acc[mi][ni] = __builtin_amdgcn_mfma_f32_16x16x32_bf16(
            __builtin_bit_cast(bf16x8, af[mi]),
            __builtin_bit_cast(bf16x8, bfv[ni]), acc[mi][ni], 0, 0, 0);

    __builtin_amdgcn_s_barrier();
    if (kt + 2 < NT) STAGE(kt + 2, cur);
    cur ^= 1;
  }

  const int lcol = l & 15, lrow = (l >> 4) << 2;
  #pragma unroll
  for (int mi = 0; mi < 4; mi++) {
    int rr = row0 + wr * 64 + mi * 16 + lrow;
    #pragma unroll
    for (int ni = 0; ni < 4; ni++) {
      int cc = wc * 64 + ni * 16 + lcol;
      if (cc < Nc) {
        #pragma unroll
        for (int r = 0; r < 4; r++)
          atomicAdd(&C[(size_t)(rr + r) * ldC + cc], acc[mi][ni][r]);
      }
    }
  }
}

// ---------------- conversion / transpose pre-passes ----------------
__global__ void cvt_k(const float* __restrict__ s, unsigned short* __restrict__ d,
                      int n8, float scale)
{
  int i = blockIdx.x * 256 + threadIdx.x;
  if (i < n8) {
    float4 a = ((const float4*)s)[2 * i], b = ((const float4*)s)[2 * i + 1];
    u16x8 w;
    w[0] = f2bf(a.x * scale); w[1] = f2bf(a.y * scale);
    w[2] = f2bf(a.z * scale); w[3] = f2bf(a.w * scale);
    w[4] = f2bf(b.x * scale); w[5] = f2bf(b.y * scale);
    w[6] = f2bf(b.z * scale); w[7] = f2bf(b.w * scale);
    ((u16x8*)d)[i] = w;
  }
}

// msk [4096][4096] fp32 -> bf16 + fused row sums (mrs pre-zeroed)
__global__ void cvt_rs_k(const float* __restrict__ s, unsigned short* __restrict__ d,
                         float* __restrict__ mrs)
{
  int i = blockIdx.x * 256 + threadIdx.x;
  float4 a = ((const float4*)s)[2 * i], b = ((const float4*)s)[2 * i + 1];
  u16x8 w;
  w[0] = f2bf(a.x); w[1] = f2bf(a.y); w[2] = f2bf(a.z); w[3] = f2bf(a.w);
  w[4] = f2bf(b.x); w[5] = f2bf(b.y); w[6] = f2bf(b.z); w[7] = f2bf(b.w);
  ((u16x8*)d)[i] = w;
  float s8 = a.x + a.y + a.z + a.w + b.x + b.y + b.z + b.w;
  float ws = wave_red_sum(s8);
  if ((threadIdx.x & 63) == 0) atomicAdd(&mrs[i >> 9], ws);
}

// [4096][3000] fp32 -> [4096][3072] bf16 zero-padded
__global__ void cvt_pad_k(const float* __restrict__ s, unsigned short* __restrict__ d)
{
  int i = blockIdx.x * 256 + threadIdx.x;
  int row = i / 384, c8 = (i - row * 384) * 8;
  u16x8 w = (u16x8)0;
  if (c8 < kIN) {
    const float* sp = s + (size_t)row * kIN + c8;
    float4 a = *(const float4*)sp, b = *(const float4*)(sp + 4);
    w[0] = f2bf(a.x); w[1] = f2bf(a.y); w[2] = f2bf(a.z); w[3] = f2bf(a.w);
    w[4] = f2bf(b.x); w[5] = f2bf(b.y); w[6] = f2bf(b.z); w[7] = f2bf(b.w);
  }
  ((u16x8*)d)[i] = w;
}

// fused: HH [4096][128] cols 0..63 -> h bf16 [4096][64] + per-row sq-norm
__global__ void cvtsq_k(const float* __restrict__ H, unsigned short* __restrict__ hb,
                        float* __restrict__ outv)
{
  int row = blockIdx.x * 4 + (threadIdx.x >> 6), j = threadIdx.x & 63;
  float v = H[(size_t)row * 128 + j];
  hb[(size_t)row * 64 + j] = f2bf(v);
  float p = wave_red_sum(v * v);
  if (j == 0) outv[row] = p;
}

// transpose+convert: src fp32 [R][C] (ld sld) -> dst bf16 (ld dld), optional relu
template<bool RELU>
__global__ void tr_k(const float* __restrict__ src, unsigned short* __restrict__ dst,
                     int R, int C, int sld, int dld)
{
  __shared__ float tile[32][33];
  int c0 = blockIdx.x * 32, r0 = blockIdx.y * 32;
  int tr_ = threadIdx.x >> 3, tc4 = (threadIdx.x & 7) << 2;
  #pragma unroll
  for (int j = 0; j < 4; j++) {
    int r = r0 + tr_, c = c0 + tc4 + j;
    float v = (r < R && c < C) ? src[(size_t)r * sld + c] : 0.f;
    if (RELU) v = fmaxf(v, 0.f);
    tile[tr_][tc4 + j] = v;
  }
  __syncthreads();
  u16x4 wv;
  #pragma unroll
  for (int j = 0; j < 4; j++) wv[j] = f2bf(tile[tc4 + j][tr_]);
  *(u16x4*)&dst[(size_t)(c0 + tr_) * dld + r0 + tc4] = wv;
}

// bf16 -> bf16 transpose: src [R][C] -> dst [C][R]
__global__ void tr_bf_k(const unsigned short* __restrict__ src,
                        unsigned short* __restrict__ dst, int R, int C)
{
  __shared__ unsigned short tile[32][36];
  int c0 = blockIdx.x * 32, r0 = blockIdx.y * 32;
  int tr_ = threadIdx.x >> 3, tc4 = (threadIdx.x & 7) << 2;
  *(u16x4*)&tile[tr_][tc4] = *(const u16x4*)&src[(size_t)(r0 + tr_) * C + c0 + tc4];
  __syncthreads();
  u16x4 w;
  #pragma unroll
  for (int j = 0; j < 4; j++) w[j] = tile[tc4 + j][tr_];
  *(u16x4*)&dst[(size_t)(c0 + tr_) * R + r0 + tc4] = w;
}

// ---------------- small fp32 GEMM (64-col weight GEMMs), optional relu(A) -----
template<bool RELU>
__global__ __launch_bounds__(256)
void gemm_small_k(const float* __restrict__ A, const float* __restrict__ B,
                  float* __restrict__ C, int M, int Nc, int K,
                  int ldA, int ldB, int ldC)
{
  __shared__ float As[16][68];
  __shared__ float Bs[16][68];
  int tid = threadIdx.x;
  int tx = tid & 15, ty = tid >> 4;
  int row0 = blockIdx.y * 64, col0 = blockIdx.x * 64;
  float acc[4][4] = {};

  for (int k0 = 0; k0 < K; k0 += 16) {
    {
      int m = tid >> 2, kk = (tid & 3) << 2;
      const float* ap = A + (size_t)(row0 + m) * ldA + k0 + kk;
      float4 v = *(const float4*)ap;
      if (RELU) {
        v.x = fmaxf(v.x, 0.f); v.y = fmaxf(v.y, 0.f);
        v.z = fmaxf(v.z, 0.f); v.w = fmaxf(v.w, 0.f);
      }
      As[kk + 0][m] = v.x; As[kk + 1][m] = v.y; As[kk + 2][m] = v.z; As[kk + 3][m] = v.w;
    }
    {
      int kk = tid >> 4, c = (tid & 15) << 2;
      const float* bp = B + (size_t)(k0 + kk) * ldB + col0 + c;
      #pragma unroll
      for (int i = 0; i < 4; i++)
        Bs[kk][c + i] = (col0 + c + i < Nc) ? bp[i] : 0.f;
    }
    __syncthreads();
    #pragma unroll
    for (int kk = 0; kk < 16; kk++) {
      float4 a4 = *(const float4*)&As[kk][ty << 2];
      float4 b4 = *(const float4*)&Bs[kk][tx << 2];
      float av[4] = {a4.x, a4.y, a4.z, a4.w};
      float bv[4] = {b4.x, b4.y, b4.z, b4.w};
      #pragma unroll
      for (int i = 0; i < 4; i++)
        #pragma unroll
        for (int j = 0; j < 4; j++)
          acc[i][j] = fmaf(av[i], bv[j], acc[i][j]);
    }
    __syncthreads();
  }
  #pragma unroll
  for (int i = 0; i < 4; i++) {
    int r = row0 + (ty << 2) + i;
    #pragma unroll
    for (int j = 0; j < 4; j++) {
      int c = col0 + (tx << 2) + j;
      if (c < Nc) C[(size_t)r * ldC + c] = acc[i][j];
    }
  }
}

// ---------------- fused Sinkhorn passes ----------------
__global__ __launch_bounds__(256)
void sink_k(float* __restrict__ P, unsigned short* __restrict__ Pb,
            const float* __restrict__ cs_in, float* __restrict__ cs_out,
            float* __restrict__ rs, int mode)
{
  int tid = threadIdx.x;
  int r0 = blockIdx.x * 8;
  float csl[16] = {};
  float cdiv[16];
  if (mode != 0) {
    #pragma unroll
    for (int t = 0; t < 4; t++) {
      float4 c4 = ((const float4*)cs_in)[tid + t * 256];
      cdiv[4 * t + 0] = 1.f / (4096.f * c4.x);
      cdiv[4 * t + 1] = 1.f / (4096.f * c4.y);
      cdiv[4 * t + 2] = 1.f / (4096.f * c4.z);
      cdiv[4 * t + 3] = 1.f / (4096.f * c4.w);
    }
  }
  for (int rr = 0; rr < 8; rr++) {
    int row = r0 + rr;
    float4* prow = (float4*)(P + (size_t)row * 4096);
    float4 r[4];
    #pragma unroll
    for (int t = 0; t < 4; t++) r[t] = prow[tid + t * 256];

    if (mode == 0) {
      float m = -3.4e38f;
      #pragma unroll
      for (int t = 0; t < 4; t++)
        m = fmaxf(m, fmaxf(fmaxf(r[t].x, r[t].y), fmaxf(r[t].z, r[t].w)));
      m = blk_red<true>(m);
      float s = 0.f;
      #pragma unroll
      for (int t = 0; t < 4; t++) {
        r[t].x = expf(r[t].x - m); r[t].y = expf(r[t].y - m);
        r[t].z = expf(r[t].z - m); r[t].w = expf(r[t].w - m);
        s += r[t].x + r[t].y + r[t].z + r[t].w;
      }
      s = blk_red<false>(s);
      float f = 1.f / (s * 4096.f);
      #pragma unroll
      for (int t = 0; t < 4; t++) {
        r[t].x *= f; r[t].y *= f; r[t].z *= f; r[t].w *= f;
        prow[tid + t * 256] = r[t];
        csl[4 * t + 0] += r[t].x; csl[4 * t + 1] += r[t].y;
        csl[4 * t + 2] += r[t].z; csl[4 * t + 3] += r[t].w;
      }
    } else {
      float s = 0.f;
      #pragma unroll
      for (int t = 0; t < 4; t++) {
        r[t].x *= cdiv[4 * t + 0]; r[t].y *= cdiv[4 * t + 1];
        r[t].z *= cdiv[4 * t + 2]; r[t].w *= cdiv[4 * t + 3];
        s += r[t].x + r[t].y + r[t].z + r[t].w;
      }
      s = blk_red<false>(s);
      if (mode == 1) {
        float f = 1.f / (4096.f * s);
        #pragma unroll
        for (int t = 0; t < 4; t++) {
          r[t].x *= f; r[t].y *= f; r[t].z *= f; r[t].w *= f;
          prow[tid + t * 256] = r[t];
          csl[4 * t + 0] += r[t].x; csl[4 * t + 1] += r[t].y;
          csl[4 * t + 2] += r[t].z; csl[4 * t + 3] += r[t].w;
        }
      } else {
        if (tid == 0) rs[row] = s;
        #pragma unroll
        for (int t = 0; t < 4; t++) {
          prow[tid + t * 256] = r[t];
          u16x4 w;
          w[0] = f2bf(r[t].x); w[1] = f2bf(r[t].y);
          w[2] = f2bf(r[t].z); w[3] = f2bf(r[t].w);
          *(u16x4*)&Pb[(size_t)row * 4096 + 4 * (tid + t * 256)] = w;
          csl[4 * t + 0] += r[t].x; csl[4 * t + 1] += r[t].y;
          csl[4 * t + 2] += r[t].z; csl[4 * t + 3] += r[t].w;
        }
      }
    }
  }
  #pragma unroll
  for (int t = 0; t < 4; t++) {
    int j = 4 * (tid + t * 256);
    atomicAdd(&cs_out[j + 0], csl[4 * t + 0]);
    atomicAdd(&cs_out[j + 1], csl[4 * t + 1]);
    atomicAdd(&cs_out[j + 2], csl[4 * t + 2]);
    atomicAdd(&cs_out[j + 3], csl[4 * t + 3]);
  }
}

__global__ void gather_k(float* __restrict__ XP, const int* __restrict__ perm)
{
  int gid = blockIdx.x * 256 + threadIdx.x;
  int i = gid >> 6, j = gid & 63;
  XP[(size_t)i * 128 + 64 + j] = XP[(size_t)perm[i] * 128 + j];
}

__global__ void readout_k(const float* __restrict__ vs2, const float* __restrict__ mrs,
                          float* __restrict__ g2)
{
  int q = blockIdx.x, j = threadIdx.x;
  float v = vs2[(size_t)q * 64 + j] / mrs[q >> 1];
  float p = v * v;
  #pragma unroll
  for (int s = 1; s < 64; s <<= 1) p += __shfl_xor(p, s, 64);
  float nrm = sqrtf(p);
  v = v / fmaxf(nrm, 1e-12f);
  g2[(size_t)q * 64 + j] = 1.f / (1.f + expf(-v));
}

__device__ __forceinline__ float bce_term(float x, float y) {
  return fmaxf(x, 0.f) - x * y + log1pf(expf(-fabsf(x)));
}

__global__ void disc_k(const float* __restrict__ G2, const float* __restrict__ W2,
                       const float* __restrict__ lab, const float* __restrict__ bptr,
                       float* __restrict__ acc)
{
  int i = blockIdx.x, j = threadIdx.x;
  float gj  = G2[(size_t)(2 * i) * 64 + j];
  float gaj = G2[(size_t)(2 * i + 1) * 64 + j];
  float hw  = W2[(size_t)(2 * i) * 64 + j];
  float haw = W2[(size_t)(2 * i + 1) * 64 + j];
  float s1 = hw * gj, s2 = haw * gj, s1a = haw * gaj, s2a = hw * gaj;
  #pragma unroll
  for (int s = 1; s < 64; s <<= 1) {
    s1  += __shfl_xor(s1, s, 64);
    s2  += __shfl_xor(s2, s, 64);
    s1a += __shfl_xor(s1a, s, 64);
    s2a += __shfl_xor(s2a, s, 64);
  }
  if (j == 0) {
    float b = bptr[0];
    float y0 = lab[i * 2 + 0], y1 = lab[i * 2 + 1];
    float t = bce_term(s1 + b, y0) + bce_term(s2 + b, y1)
            + bce_term(s1a + b, y0) + bce_term(s2a + b, y1);
    atomicAdd(&acc[SL], t);
  }
}

__global__ __launch_bounds__(256)
void finalize_k(const float* __restrict__ acc, const float* __restrict__ cs,
                float* __restrict__ out)
{
  int tid = threadIdx.x;
  float invm2 = 1.f / (float)kN;
  float t = 0.f;
  for (int j = tid; j < kN; j += 256) {
    float q = cs[j];
    t += q * (logf(q) - invm2);
  }
  t = blk_red<false>(t);
  if (tid == 0) {
    float kld_pq = t * invm2;
    float kld_pp = invm2 * (logf(invm2) - invm2);
    out[0] = acc[SL] / (2.f * (float)kN);
    out[1] = acc[FEAT] / ((float)kN * (float)kIN);
    out[2] = acc[ALN];
    out[3] = (acc[FXA] + acc[FXB]) / ((float)kN * (float)kIN);
    out[4] = sqrtf(acc[SM1]) / (float)kN + sqrtf(acc[SM2]) / (float)kN;
    out[5] = (kld_pq - kld_pp) * (float)kN;
    out[6] = -acc[SPS];
  }
}

extern "C" void kernel_launch(void* const* d_in, const int* in_sizes, int n_in,
                              void* d_out, int out_size, void* d_ws, size_t ws_size,
                              hipStream_t stream)
{
  (void)in_sizes; (void)n_in; (void)out_size; (void)ws_size;
  const float* feat  = (const float*)d_in[0];
  const float* adjs  = (const float*)d_in[1];
  const float* gmask = (const float*)d_in[2];
  const float* labs  = (const float*)d_in[3];
  const float* dists = (const float*)d_in[4];
  const int*   perms = (const int*)d_in[5];
  const float* encW  = (const float*)d_in[6];
  const float* decW  = (const float*)d_in[7];
  const float* MsW   = (const float*)d_in[8];
  const float* discW = (const float*)d_in[9];
  const float* discb = (const float*)d_in[10];
  float* out = (float*)d_out;

  const size_t SZNN = (size_t)kN * kN;

  char* cur = (char*)d_ws;
  auto alloc = [&](size_t bytes) {
    char* p = cur;
    cur += (bytes + 255) & ~(size_t)255;
    return p;
  };
  float* P            = (float*)alloc(SZNN * 4);          // fp32 P; later Tb1
  unsigned short* Pb  = (unsigned short*)alloc(SZNN * 2);
  unsigned short* PbT = (unsigned short*)alloc(SZNN * 2);
  unsigned short* Db  = (unsigned short*)alloc(SZNN * 2); // D bf16; also ftb2
  unsigned short* ajb = (unsigned short*)alloc(SZNN * 2); // adj/msk bf16; ftb; Tb2
  unsigned short* xb0 = (unsigned short*)alloc((size_t)kN * kINp * 2);
  unsigned short* xb1 = (unsigned short*)alloc((size_t)kN * kINp * 2);
  unsigned short* dWtb= (unsigned short*)alloc((size_t)kINp * kLAT * 2);
  unsigned short* ahb = (unsigned short*)alloc((size_t)kN * kLAT * 2);
  unsigned short* encWtp = (unsigned short*)alloc((size_t)128 * kINp * 2);
  unsigned short* XPt = (unsigned short*)alloc((size_t)128 * kN * 2);
  unsigned short* hbTp= (unsigned short*)alloc((size_t)128 * kN * 2);
  unsigned short* HRt = (unsigned short*)alloc((size_t)128 * kN * 2);
  unsigned short* smb = (unsigned short*)alloc((size_t)kN * kLAT * 2);
  unsigned short* tmb = (unsigned short*)alloc((size_t)kN * kLAT * 2);
  unsigned short* h0b = (unsigned short*)alloc((size_t)kN * kLAT * 2);
  unsigned short* h1b = (unsigned short*)alloc((size_t)kN * kLAT * 2);
  float* XP  = (float*)alloc((size_t)kN * 128 * 4);
  float* HH0 = (float*)alloc((size_t)kN * 128 * 4);
  float* HH1 = (float*)alloc((size_t)kN * 128 * 4);
  float* VS  = (float*)alloc((size_t)kN * 128 * 4);
  float* G2  = (float*)alloc((size_t)kN * 128 * 4);
  float* W2  = (float*)alloc((size_t)kN * 128 * 4);
  float* SM_ = (float*)alloc((size_t)kN * kLAT * 4);
  float* TM_ = (float*)alloc((size_t)kN * kLAT * 4);
  float* ah  = (float*)alloc((size_t)kN * kLAT * 4);
  float* sns = (float*)alloc(kN * 4);
  float* snt = (float*)alloc(kN * 4);
  float* rs  = (float*)alloc(kN * 4);
  float* cs  = (float*)alloc(kN * 4);
  float* csA = (float*)alloc(kN * 4);
  float* csB = (float*)alloc(kN * 4);
  float* mrs = (float*)alloc(kN * 4);
  float* acc = (float*)alloc(NSLOT * 4);

  unsigned short* Tb1 = (unsigned short*)P;   // alias: fp32 P dead before Tb1 written
  unsigned short* ftb = ajb;                  // alias: adj/msk bf16 dead after slices
  unsigned short* ftb2= Db;                   // alias: Db unused until maintain
  unsigned short* Tb2 = ajb;                  // alias: ftb dead after merged FX

  hipMemsetAsync(acc, 0, NSLOT * sizeof(float), stream);

  // ---------------- per-slice losses ----------------
  for (int k = 0; k < 2; k++) {
    const float* x    = feat  + (size_t)k * kN * kIN;
    const float* adj  = adjs  + (size_t)k * SZNN;
    const float* msk  = gmask + (size_t)k * SZNN;
    const float* lab  = labs  + (size_t)k * kN * 2;
    const int*   perm = perms + (size_t)k * kN;
    const float* eW   = encW  + (size_t)k * kIN * kLAT;
    const float* dW   = decW  + (size_t)k * kLAT * kIN;
    float* HHk = (k == 0) ? HH0 : HH1;
    unsigned short* xbk = (k == 0) ? xb0 : xb1;

    cvt_pad_k<<<6144, 256, 0, stream>>>(x, xbk);
    hipMemsetAsync(encWtp, 0, (size_t)128 * kINp * 2, stream);
    tr_k<false><<<dim3(2, (kIN + 31) / 32), 256, 0, stream>>>(eW, encWtp, kIN, kLAT, kLAT, kINp);
    hipMemsetAsync(XP, 0, (size_t)kN * 128 * 4, stream);
    ns_mfma_k<<<512, 256, 0, stream>>>(xbk, encWtp, XP, kLAT, kINp, kINp / 16, 128);
    gather_k<<<kN * 64 / 256, 256, 0, stream>>>(XP, perm);
    tr_k<false><<<dim3(4, 128), 256, 0, stream>>>(XP, XPt, kN, 128, 128, kN);
    cvt_k<<<(int)(SZNN / 8 / 256), 256, 0, stream>>>(adj, ajb, (int)(SZNN / 8), 1.f);
    hipMemsetAsync(HHk, 0, (size_t)kN * 128 * 4, stream);
    ns_mfma_k<<<512, 256, 0, stream>>>(ajb, XPt, HHk, 128, kN, kN / 16, 128);
    hipMemsetAsync(hbTp, 0, (size_t)128 * kN * 2, stream);
    tr_k<false><<<dim3(2, 128), 256, 0, stream>>>(HHk, hbTp, kN, kLAT, 128, kN);
    hipMemsetAsync(ah, 0, (size_t)kN * kLAT * 4, stream);
    ns_mfma_k<<<512, 256, 0, stream>>>(ajb, hbTp, ah, kLAT, kN, kN / 16, kLAT);
    cvt_k<<<128, 256, 0, stream>>>(ah, ahb, kN * kLAT / 8, 1.f);
    tr_k<false><<<dim3(kINp / 32, 2), 256, 0, stream>>>(dW, dWtb, kLAT, kIN, kIN, kLAT);
    bt_mfma_k<2, 1><<<(kINp / 128) * 32, 256, 0, stream>>>(
        ahb, dWtb, nullptr, nullptr, xbk, nullptr, nullptr, &acc[FEAT],
        kINp / 128, kIN, kLAT, kINp);
    tr_k<true><<<dim3(4, 128), 256, 0, stream>>>(HHk, HRt, kN, 128, 128, kN);
    hipMemsetAsync(mrs, 0, kN * 4, stream);
    cvt_rs_k<<<(int)(SZNN / 8 / 256), 256, 0, stream>>>(msk, ajb, mrs);
    hipMemsetAsync(VS, 0, (size_t)kN * 128 * 4, stream);
    ns_mfma_k<<<512, 256, 0, stream>>>(ajb, HRt, VS, 128, kN, kN / 16, 128);
    readout_k<<<2 * kN, 64, 0, stream>>>(VS, mrs, G2);
    gemm_small_k<true><<<dim3(1, 128), 256, 0, stream>>>(HHk, discW, W2, 2 * kN, kLAT,
                                                         kLAT, kLAT, kLAT, kLAT);
    disc_k<<<kN, 64, 0, stream>>>(G2, W2, lab, discb, acc);
  }

  // ---------------- alignment losses ----------------
  const float* D0 = dists;
  const float* D1 = dists + SZNN;

  gemm_small_k<false><<<dim3(1, 64), 256, 0, stream>>>(HH0, MsW, SM_, kN, kLAT, kLAT,
                                                       128, kLAT, kLAT);
  gemm_small_k<false><<<dim3(1, 64), 256, 0, stream>>>(HH1, MsW, TM_, kN, kLAT, kLAT,
                                                       128, kLAT, kLAT);
  cvt_k<<<128, 256, 0, stream>>>(SM_, smb, kN * kLAT / 8, 0.125f);
  cvt_k<<<128, 256, 0, stream>>>(TM_, tmb, kN * kLAT / 8, 1.f);
  // P = srcM @ tgtM^T / 8  (128-tile MFMA, fp32 store)
  bt_mfma_k<1, 0><<<1024, 256, 0, stream>>>(smb, tmb, nullptr, P, nullptr, nullptr, nullptr,
                                            nullptr, 32, kN, kLAT, 0);

  // fused sinkhorn: softmax + 3 iters + final marginals + bf16 P, 4 passes
  hipMemsetAsync(csA, 0, kN * 4, stream);
  sink_k<<<512, 256, 0, stream>>>(P, nullptr, nullptr, csA, nullptr, 0);
  hipMemsetAsync(csB, 0, kN * 4, stream);
  sink_k<<<512, 256, 0, stream>>>(P, nullptr, csA, csB, nullptr, 1);
  hipMemsetAsync(csA, 0, kN * 4, stream);
  sink_k<<<512, 256, 0, stream>>>(P, nullptr, csB, csA, nullptr, 1);
  hipMemsetAsync(cs, 0, kN * 4, stream);
  sink_k<<<512, 256, 0, stream>>>(P, Pb, csA, cs, rs, 2);

  // PbT = bf16(P^T) — last read of fp32 P
  tr_k<false><<<dim3(kN / 32, kN / 32), 256, 0, stream>>>(P, PbT, kN, kN, kN, kN);

  // align + sparsity: h0@h1^T (EPI3); fused h-bf16 + sqnorms
  cvtsq_k<<<1024, 256, 0, stream>>>(HH0, h0b, sns);
  cvtsq_k<<<1024, 256, 0, stream>>>(HH1, h1b, snt);
  bt_mfma_k<3, 1><<<1024, 256, 0, stream>>>(h0b, h1b, nullptr, nullptr, Pb, sns, snt, acc,
                                            32, kN, kLAT, kN);

  // loss_align_fix: merged FXA+FXB in ONE grid-stride dispatch (1536 tiles, 0 tail)
  tr_bf_k<<<dim3(kINp / 32, kN / 32), 256, 0, stream>>>(xb1, ftb, kN, kINp);
  tr_bf_k<<<dim3(kINp / 32, kN / 32), 256, 0, stream>>>(xb0, ftb2, kN, kINp);
  bt2_mfma_k<1, 0><<<1024, 256, 0, stream>>>(
      Pb,  ftb,  xb0, rs, nullptr, &acc[FXA],
      PbT, ftb2, xb1, cs, nullptr, &acc[FXB],
      kINp / 128, kIN, kN, kINp, 2 * (kINp / 128) * 32, (kINp / 128) * 32);

  // loss_maintain: Tb1 = (P@D1)/rs ; Tb2 = (P^T@D0)/cs ; merged sym reduce
  cvt_k<<<(int)(SZNN / 8 / 256), 256, 0, stream>>>(D1, Db, (int)(SZNN / 8), 1.f);
  bt_mfma_k<0, 0><<<1024, 256, 0, stream>>>(Pb, Db, Tb1, nullptr, nullptr, rs, nullptr,
                                            nullptr, 32, kN, kN, 0);
  cvt_k<<<(int)(SZNN / 8 / 256), 256, 0, stream>>>(D0, Db, (int)(SZNN / 8), 1.f);
  bt_mfma_k<0, 0><<<1024, 256, 0, stream>>>(PbT, Db, Tb2, nullptr, nullptr, cs, nullptr,
                                            nullptr, 32, kN, kN, 0);
  // merged SM1+SM2: 1056 triangular tiles over 1024 blocks (blocks 0..31 take 2)
  bt2_mfma_k<0, 1><<<1024, 256, 0, stream>>>(
      Tb1, Pb,  D0, nullptr, rs, &acc[SM1],
      Tb2, PbT, D1, nullptr, cs, &acc[SM2],
      32, kN, kN, kN, 1056, 528);

  finalize_k<<<1, 256, 0, stream>>>(acc, cs, out);
}

// Round 12
// 1986.536 us; speedup vs baseline: 1.0732x; 1.0732x over previous
//
#include <hip/hip_runtime.h>
#include <cmath>

// Problem constants
constexpr int kN   = 4096;
constexpr int kIN  = 3000;
constexpr int kINp = 3072;   // kIN padded to 128-multiple
constexpr int kLAT = 64;

enum { SL = 0, FEAT, ALN, FXA, FXB, SM1, SM2, SPS, NSLOT };

typedef __bf16 bf16x8 __attribute__((ext_vector_type(8)));
typedef float f32x4 __attribute__((ext_vector_type(4)));
typedef unsigned short u16x8 __attribute__((ext_vector_type(8)));
typedef unsigned short u16x4 __attribute__((ext_vector_type(4)));

// ---------------- reduction helpers ----------------
template<bool IS_MAX>
__device__ __forceinline__ float blk_red(float v) {
  __shared__ float buf[8];
  #pragma unroll
  for (int s = 32; s > 0; s >>= 1) {
    float o = __shfl_down(v, s, 64);
    v = IS_MAX ? fmaxf(v, o) : (v + o);
  }
  int lane = threadIdx.x & 63, wv = threadIdx.x >> 6, nw = blockDim.x >> 6;
  __syncthreads();
  if (lane == 0) buf[wv] = v;
  __syncthreads();
  float r = buf[0];
  for (int i = 1; i < nw; i++) r = IS_MAX ? fmaxf(r, buf[i]) : (r + buf[i]);
  __syncthreads();   // protect buf reuse across consecutive calls
  return r;
}

__device__ __forceinline__ float wave_red_sum(float v) {
  #pragma unroll
  for (int s = 32; s > 0; s >>= 1) v += __shfl_down(v, s, 64);
  return v;
}

// fp32 -> bf16 RNE ; bf16 -> fp32
__device__ __forceinline__ unsigned short f2bf(float f) {
  unsigned u = __builtin_bit_cast(unsigned, f);
  u += 0x7fffu + ((u >> 16) & 1u);
  return (unsigned short)(u >> 16);
}
__device__ __forceinline__ float bf2f(unsigned short h) {
  return __builtin_bit_cast(float, (unsigned)h << 16);
}

// async global->LDS, 16B per lane
__device__ __forceinline__ void gload16(const unsigned short* g, unsigned short* l) {
  __builtin_amdgcn_global_load_lds(
      (const __attribute__((address_space(1))) unsigned int*)g,
      (__attribute__((address_space(3))) unsigned int*)l, 16, 0, 0);
}

#define VMW(n) asm volatile("s_waitcnt vmcnt(" #n ")" ::: "memory")

// triangular decode: lu in [0,528) -> upper-tri tile (by,bx) of 32x32 grid
__device__ __forceinline__ void tri_decode(int lu, int& bx, int& by) {
  int x = lu & 7, i = lu >> 3;
  int u = x * 66 + i;
  float disc = 4225.f - 8.f * (float)u;
  by = (int)((65.f - sqrtf(fmaxf(disc, 0.f))) * 0.5f);
  while (by > 0 && 32 * by - by * (by - 1) / 2 > u) by--;
  while (32 * (by + 1) - (by + 1) * by / 2 <= u) by++;
  bx = by + (u - (32 * by - by * (by - 1) / 2));
}

// ================== 128-tile bf16 MFMA GEMM: C = A @ Bt^T ==================
// 3-deep pipeline, counted vmcnt. Dense strip decode or sym triangular (528).
// EPI 0: Cb = bf16(acc / rowdiv[r])
// EPI 1: Cf = acc (fp32)
// EPI 2: slot += wgt*sum (X - acc/rd/cd)^2 (X fp32 XBF=0 / bf16 XBF=1)
// EPI 3: align+sparsity epilogue
template<int EPI, int XBF>
__global__ __launch_bounds__(256)
void bt_mfma_k(const unsigned short* __restrict__ A, const unsigned short* __restrict__ Bt,
               unsigned short* __restrict__ Cb, float* __restrict__ Cf,
               const void* __restrict__ Xv,
               const float* __restrict__ rowdiv, const float* __restrict__ coldiv,
               float* __restrict__ slot, int gx, int Nc, int K, int ldX, int sym)
{
  __shared__ unsigned short AB[3 * 8192];

  int orig = blockIdx.x;
  int bx, by;
  if (EPI == 2 && sym) {
    tri_decode(orig, bx, by);
  } else {
    int x = orig & 7, tt = orig >> 3;
    bx = tt >> 2;
    by = x * 4 + (tt & 3);
  }
  const int row0 = by * 128, col0 = bx * 128;

  const int t = threadIdx.x, l = t & 63, wv = t >> 6;
  const int wr = wv >> 1, wc = wv & 1;
  const int lr = l & 15, lkh = (l >> 4) << 3;

  f32x4 acc[4][4];
  #pragma unroll
  for (int i = 0; i < 4; i++)
    #pragma unroll
    for (int j = 0; j < 4; j++) acc[i][j] = (f32x4){0.f, 0.f, 0.f, 0.f};

  const int srow = l >> 2;
  const int sk   = (l & 3) << 3;
  const unsigned short* Ab = A  + (size_t)(row0 + srow) * K + sk;
  const unsigned short* Bb = Bt + (size_t)(col0 + srow) * K + sk;

  const int NT = K >> 5;

  auto STAGE = [&](int kt, int buf) {
    unsigned short* As = AB + buf * 8192;
    unsigned short* Bs = As + 4096;
    int k0 = kt << 5;
    #pragma unroll
    for (int h2 = 0; h2 < 2; h2++) {
      int c = wv * 2 + h2;
      gload16(Ab + (size_t)c * 16 * K + k0, As + c * 512);
      gload16(Bb + (size_t)c * 16 * K + k0, Bs + c * 512);
    }
  };

  STAGE(0, 0);
  if (NT > 1) STAGE(1, 1);
  if (NT > 2) STAGE(2, 2);
  int cur = 0;

  for (int kt = 0; kt < NT; ++kt) {
    int ahead = NT - 1 - kt;
    if (ahead >= 2)      { VMW(8); }
    else if (ahead == 1) { VMW(4); }
    else                 { VMW(0); }
    __builtin_amdgcn_sched_barrier(0);
    __builtin_amdgcn_s_barrier();

    const unsigned short* As = AB + cur * 8192;
    const unsigned short* Bs = As + 4096;
    u16x8 af[4], bfv[4];
    #pragma unroll
    for (int mi = 0; mi < 4; mi++)
      af[mi] = *(const u16x8*)&As[(wr * 64 + mi * 16 + lr) * 32 + lkh];
    #pragma unroll
    for (int ni = 0; ni < 4; ni++)
      bfv[ni] = *(const u16x8*)&Bs[(wc * 64 + ni * 16 + lr) * 32 + lkh];
    #pragma unroll
    for (int mi = 0; mi < 4; mi++)
      #pragma unroll
      for (int ni = 0; ni < 4; ni++)
        acc[mi][ni] = __builtin_amdgcn_mfma_f32_16x16x32_bf16(
            __builtin_bit_cast(bf16x8, af[mi]),
            __builtin_bit_cast(bf16x8, bfv[ni]), acc[mi][ni], 0, 0, 0);

    __builtin_amdgcn_s_barrier();
    if (kt + 3 < NT) STAGE(kt + 3, cur);
    cur = (cur == 2) ? 0 : cur + 1;
  }

  const int lcol = l & 15, lrow = (l >> 4) << 2;
  if (EPI == 0) {
    #pragma unroll
    for (int mi = 0; mi < 4; mi++) {
      int rr = row0 + wr * 64 + mi * 16 + lrow;
      #pragma unroll
      for (int ni = 0; ni < 4; ni++) {
        int cc = col0 + wc * 64 + ni * 16 + lcol;
        #pragma unroll
        for (int r = 0; r < 4; r++) {
          float v = acc[mi][ni][r];
          if (rowdiv) v /= rowdiv[rr + r];
          Cb[(size_t)(rr + r) * 4096 + cc] = f2bf(v);
        }
      }
    }
  } else if (EPI == 1) {
    #pragma unroll
    for (int mi = 0; mi < 4; mi++) {
      int rr = row0 + wr * 64 + mi * 16 + lrow;
      #pragma unroll
      for (int ni = 0; ni < 4; ni++) {
        int cc = col0 + wc * 64 + ni * 16 + lcol;
        #pragma unroll
        for (int r = 0; r < 4; r++)
          Cf[(size_t)(rr + r) * 4096 + cc] = acc[mi][ni][r];
      }
    }
  } else if (EPI == 2) {
    const float* Xf = (const float*)Xv;
    const unsigned short* Xh = (const unsigned short*)Xv;
    float part = 0.f;
    #pragma unroll
    for (int mi = 0; mi < 4; mi++) {
      int rr = row0 + wr * 64 + mi * 16 + lrow;
      #pragma unroll
      for (int ni = 0; ni < 4; ni++) {
        int cc = col0 + wc * 64 + ni * 16 + lcol;
        if (cc < Nc) {
          float cd = coldiv ? coldiv[cc] : 1.f;
          #pragma unroll
          for (int r = 0; r < 4; r++) {
            float v = acc[mi][ni][r];
            if (rowdiv) v /= rowdiv[rr + r];
            v /= cd;
            size_t xi = (size_t)(rr + r) * ldX + cc;
            float xval = XBF ? bf2f(Xh[xi]) : Xf[xi];
            float d = xval - v;
            part = fmaf(d, d, part);
          }
        }
      }
    }
    part = blk_red<false>(part);
    if (t == 0) {
      float wgt = (sym && col0 > row0) ? 2.f : 1.f;
      atomicAdd(slot, part * wgt);
    }
  } else { // EPI 3
    const unsigned short* Ph = (const unsigned short*)Xv;
    float a = 0.f, sp = 0.f;
    #pragma unroll
    for (int mi = 0; mi < 4; mi++) {
      int rr = row0 + wr * 64 + mi * 16 + lrow;
      #pragma unroll
      for (int ni = 0; ni < 4; ni++) {
        int cc = col0 + wc * 64 + ni * 16 + lcol;
        #pragma unroll
        for (int r = 0; r < 4; r++) {
          float g = acc[mi][ni][r];
          float p = bf2f(Ph[(size_t)(rr + r) * ldX + cc]);
          float d2 = rowdiv[rr + r] + coldiv[cc] - 2.f * g;
          a = fmaf(p, sqrtf(fmaxf(d2, 1e-12f)), a);
          sp = fmaf(p, logf(p + 1e-10f), sp);
        }
      }
    }
    a = blk_red<false>(a);
    sp = blk_red<false>(sp);
    if (t == 0) { atomicAdd(&slot[ALN], a); atomicAdd(&slot[SPS], sp); }
  }
}

// ===== flat merged FX reduce: 2 GEMM-reduces in one dispatch (no loop) =====
// blocks [0,split) -> set0; [split, 2*split) -> set1. Strip decode per set.
// slot += sum (X(bf16) - acc/rowdiv[r])^2. L3-safe: 164 MB combined set.
__global__ __launch_bounds__(256)
void bt2f_mfma_k(const unsigned short* __restrict__ A0, const unsigned short* __restrict__ B0,
                 const unsigned short* __restrict__ X0, const float* __restrict__ rd0,
                 float* __restrict__ slot0,
                 const unsigned short* __restrict__ A1, const unsigned short* __restrict__ B1,
                 const unsigned short* __restrict__ X1, const float* __restrict__ rd1,
                 float* __restrict__ slot1,
                 int gx, int Nc, int K, int ldX, int split)
{
  __shared__ unsigned short AB[3 * 8192];

  int u = blockIdx.x;
  const int s1 = (u >= split);
  const int lu = s1 ? (u - split) : u;
  const unsigned short* A  = s1 ? A1 : A0;
  const unsigned short* Bt = s1 ? B1 : B0;
  const unsigned short* Xh = s1 ? X1 : X0;
  const float* rowdiv      = s1 ? rd1 : rd0;
  float* slot              = s1 ? slot1 : slot0;

  int x = lu & 7, tt = lu >> 3;
  int bx = tt >> 2;
  int by = x * 4 + (tt & 3);
  const int row0 = by * 128, col0 = bx * 128;

  const int t = threadIdx.x, l = t & 63, wv = t >> 6;
  const int wr = wv >> 1, wc = wv & 1;
  const int lr = l & 15, lkh = (l >> 4) << 3;

  f32x4 acc[4][4];
  #pragma unroll
  for (int i = 0; i < 4; i++)
    #pragma unroll
    for (int j = 0; j < 4; j++) acc[i][j] = (f32x4){0.f, 0.f, 0.f, 0.f};

  const int srow = l >> 2;
  const int sk   = (l & 3) << 3;
  const unsigned short* Ab = A  + (size_t)(row0 + srow) * K + sk;
  const unsigned short* Bb = Bt + (size_t)(col0 + srow) * K + sk;

  const int NT = K >> 5;

  auto STAGE = [&](int kt, int buf) {
    unsigned short* As = AB + buf * 8192;
    unsigned short* Bs = As + 4096;
    int k0 = kt << 5;
    #pragma unroll
    for (int h2 = 0; h2 < 2; h2++) {
      int c = wv * 2 + h2;
      gload16(Ab + (size_t)c * 16 * K + k0, As + c * 512);
      gload16(Bb + (size_t)c * 16 * K + k0, Bs + c * 512);
    }
  };

  STAGE(0, 0);
  if (NT > 1) STAGE(1, 1);
  if (NT > 2) STAGE(2, 2);
  int cur = 0;

  for (int kt = 0; kt < NT; ++kt) {
    int ahead = NT - 1 - kt;
    if (ahead >= 2)      { VMW(8); }
    else if (ahead == 1) { VMW(4); }
    else                 { VMW(0); }
    __builtin_amdgcn_sched_barrier(0);
    __builtin_amdgcn_s_barrier();

    const unsigned short* As = AB + cur * 8192;
    const unsigned short* Bs = As + 4096;
    u16x8 af[4], bfv[4];
    #pragma unroll
    for (int mi = 0; mi < 4; mi++)
      af[mi] = *(const u16x8*)&As[(wr * 64 + mi * 16 + lr) * 32 + lkh];
    #pragma unroll
    for (int ni = 0; ni < 4; ni++)
      bfv[ni] = *(const u16x8*)&Bs[(wc * 64 + ni * 16 + lr) * 32 + lkh];
    #pragma unroll
    for (int mi = 0; mi < 4; mi++)
      #pragma unroll
      for (int ni = 0; ni < 4; ni++)
        acc[mi][ni] = __builtin_amdgcn_mfma_f32_16x16x32_bf16(
            __builtin_bit_cast(bf16x8, af[mi]),
            __builtin_bit_cast(bf16x8, bfv[ni]), acc[mi][ni], 0, 0, 0);

    __builtin_amdgcn_s_barrier();
    if (kt + 3 < NT) STAGE(kt + 3, cur);
    cur = (cur == 2) ? 0 : cur + 1;
  }

  const int lcol = l & 15, lrow = (l >> 4) << 2;
  float part = 0.f;
  #pragma unroll
  for (int mi = 0; mi < 4; mi++) {
    int rr = row0 + wr * 64 + mi * 16 + lrow;
    #pragma unroll
    for (int ni = 0; ni < 4; ni++) {
      int cc = col0 + wc * 64 + ni * 16 + lcol;
      if (cc < Nc) {
        #pragma unroll
        for (int r = 0; r < 4; r++) {
          float v = acc[mi][ni][r] / rowdiv[rr + r];
          float d = bf2f(Xh[(size_t)(rr + r) * ldX + cc]) - v;
          part = fmaf(d, d, part);
        }
      }
    }
  }
  part = blk_red<false>(part);
  if (t == 0) atomicAdd(slot, part);
}

// ============ narrow split-K bf16 MFMA: C[4096][Nc<=128] += A @ Bt^T ============
__global__ __launch_bounds__(256)
void ns_mfma_k(const unsigned short* __restrict__ A, const unsigned short* __restrict__ Bt,
               float* __restrict__ C, int Nc, int K, int KC, int ldC)
{
  __shared__ unsigned short AB[2 * 8192];
  int ks = blockIdx.x & 15, strip = blockIdx.x >> 4;
  const int row0 = strip * 128;
  const int kbase = ks * KC;

  const int t = threadIdx.x, l = t & 63, wv = t >> 6;
  const int wr = wv >> 1, wc = wv & 1;
  const int lr = l & 15, lkh = (l >> 4) << 3;

  f32x4 acc[4][4];
  #pragma unroll
  for (int i = 0; i < 4; i++)
    #pragma unroll
    for (int j = 0; j < 4; j++) acc[i][j] = (f32x4){0.f, 0.f, 0.f, 0.f};

  const int srow = l >> 2;
  const int sk   = (l & 3) << 3;
  const unsigned short* Ab = A  + (size_t)(row0 + srow) * K + kbase + sk;
  const unsigned short* Bb = Bt + (size_t)srow * K + kbase + sk;

  const int NT = KC >> 5;

  auto STAGE = [&](int kt, int buf) {
    unsigned short* As = AB + buf * 8192;
    unsigned short* Bs = As + 4096;
    int k0 = kt << 5;
    #pragma unroll
    for (int h2 = 0; h2 < 2; h2++) {
      int c = wv * 2 + h2;
      gload16(Ab + (size_t)c * 16 * K + k0, As + c * 512);
      gload16(Bb + (size_t)c * 16 * K + k0, Bs + c * 512);
    }
  };

  STAGE(0, 0);
  if (NT > 1) STAGE(1, 1);
  int cur = 0;

  for (int kt = 0; kt < NT; ++kt) {
    if (kt + 1 < NT) { VMW(4); }
    else             { VMW(0); }
    __builtin_amdgcn_sched_barrier(0);
    __builtin_amdgcn_s_barrier();

    const unsigned short* As = AB + cur * 8192;
    const unsigned short* Bs = As + 4096;
    u16x8 af[4], bfv[4];
    #pragma unroll
    for (int mi = 0; mi < 4; mi++)
      af[mi] = *(const u16x8*)&As[(wr * 64 + mi * 16 + lr) * 32 + lkh];
    #pragma unroll
    for (int ni = 0; ni < 4; ni++)
      bfv[ni] = *(const u16x8*)&Bs[(wc * 64 + ni * 16 + lr) * 32 + lkh];
    #pragma unroll
    for (int mi = 0; mi < 4; mi++)
      #pragma unroll
      for (int ni = 0; ni < 4; ni++)
        acc[mi][ni] = __builtin_amdgcn_mfma_f32_16x16x32_bf16(
            __builtin_bit_cast(bf16x8, af[mi]),
            __builtin_bit_cast(bf16x8, bfv[ni]), acc[mi][ni], 0, 0, 0);

    __builtin_amdgcn_s_barrier();
    if (kt + 2 < NT) STAGE(kt + 2, cur);
    cur ^= 1;
  }

  const int lcol = l & 15, lrow = (l >> 4) << 2;
  #pragma unroll
  for (int mi = 0; mi < 4; mi++) {
    int rr = row0 + wr * 64 + mi * 16 + lrow;
    #pragma unroll
    for (int ni = 0; ni < 4; ni++) {
      int cc = wc * 64 + ni * 16 + lcol;
      if (cc < Nc) {
        #pragma unroll
        for (int r = 0; r < 4; r++)
          atomicAdd(&C[(size_t)(rr + r) * ldC + cc], acc[mi][ni][r]);
      }
    }
  }
}

// ---------------- conversion / transpose pre-passes ----------------
__global__ void cvt_k(const float* __restrict__ s, unsigned short* __restrict__ d,
                      int n8, float scale)
{
  int i = blockIdx.x * 256 + threadIdx.x;
  if (i < n8) {
    float4 a = ((const float4*)s)[2 * i], b = ((const float4*)s)[2 * i + 1];
    u16x8 w;
    w[0] = f2bf(a.x * scale); w[1] = f2bf(a.y * scale);
    w[2] = f2bf(a.z * scale); w[3] = f2bf(a.w * scale);
    w[4] = f2bf(b.x * scale); w[5] = f2bf(b.y * scale);
    w[6] = f2bf(b.z * scale); w[7] = f2bf(b.w * scale);
    ((u16x8*)d)[i] = w;
  }
}

// msk [4096][4096] fp32 -> bf16 + fused row sums (mrs pre-zeroed)
__global__ void cvt_rs_k(const float* __restrict__ s, unsigned short* __restrict__ d,
                         float* __restrict__ mrs)
{
  int i = blockIdx.x * 256 + threadIdx.x;
  float4 a = ((const float4*)s)[2 * i], b = ((const float4*)s)[2 * i + 1];
  u16x8 w;
  w[0] = f2bf(a.x); w[1] = f2bf(a.y); w[2] = f2bf(a.z); w[3] = f2bf(a.w);
  w[4] = f2bf(b.x); w[5] = f2bf(b.y); w[6] = f2bf(b.z); w[7] = f2bf(b.w);
  ((u16x8*)d)[i] = w;
  float s8 = a.x + a.y + a.z + a.w + b.x + b.y + b.z + b.w;
  float ws = wave_red_sum(s8);
  if ((threadIdx.x & 63) == 0) atomicAdd(&mrs[i >> 9], ws);
}

// [4096][3000] fp32 -> [4096][3072] bf16 zero-padded
__global__ void cvt_pad_k(const float* __restrict__ s, unsigned short* __restrict__ d)
{
  int i = blockIdx.x * 256 + threadIdx.x;
  int row = i / 384, c8 = (i - row * 384) * 8;
  u16x8 w = (u16x8)0;
  if (c8 < kIN) {
    const float* sp = s + (size_t)row * kIN + c8;
    float4 a = *(const float4*)sp, b = *(const float4*)(sp + 4);
    w[0] = f2bf(a.x); w[1] = f2bf(a.y); w[2] = f2bf(a.z); w[3] = f2bf(a.w);
    w[4] = f2bf(b.x); w[5] = f2bf(b.y); w[6] = f2bf(b.z); w[7] = f2bf(b.w);
  }
  ((u16x8*)d)[i] = w;
}

// fused: HH [4096][128] cols 0..63 -> h bf16 [4096][64] + per-row sq-norm
__global__ void cvtsq_k(const float* __restrict__ H, unsigned short* __restrict__ hb,
                        float* __restrict__ outv)
{
  int row = blockIdx.x * 4 + (threadIdx.x >> 6), j = threadIdx.x & 63;
  float v = H[(size_t)row * 128 + j];
  hb[(size_t)row * 64 + j] = f2bf(v);
  float p = wave_red_sum(v * v);
  if (j == 0) outv[row] = p;
}

// transpose+convert: src fp32 [R][C] (ld sld) -> dst bf16 (ld dld), optional relu
template<bool RELU>
__global__ void tr_k(const float* __restrict__ src, unsigned short* __restrict__ dst,
                     int R, int C, int sld, int dld)
{
  __shared__ float tile[32][33];
  int c0 = blockIdx.x * 32, r0 = blockIdx.y * 32;
  int tr_ = threadIdx.x >> 3, tc4 = (threadIdx.x & 7) << 2;
  #pragma unroll
  for (int j = 0; j < 4; j++) {
    int r = r0 + tr_, c = c0 + tc4 + j;
    float v = (r < R && c < C) ? src[(size_t)r * sld + c] : 0.f;
    if (RELU) v = fmaxf(v, 0.f);
    tile[tr_][tc4 + j] = v;
  }
  __syncthreads();
  u16x4 wv;
  #pragma unroll
  for (int j = 0; j < 4; j++) wv[j] = f2bf(tile[tc4 + j][tr_]);
  *(u16x4*)&dst[(size_t)(c0 + tr_) * dld + r0 + tc4] = wv;
}

// bf16 -> bf16 transpose: src [R][C] -> dst [C][R]
__global__ void tr_bf_k(const unsigned short* __restrict__ src,
                        unsigned short* __restrict__ dst, int R, int C)
{
  __shared__ unsigned short tile[32][36];
  int c0 = blockIdx.x * 32, r0 = blockIdx.y * 32;
  int tr_ = threadIdx.x >> 3, tc4 = (threadIdx.x & 7) << 2;
  *(u16x4*)&tile[tr_][tc4] = *(const u16x4*)&src[(size_t)(r0 + tr_) * C + c0 + tc4];
  __syncthreads();
  u16x4 w;
  #pragma unroll
  for (int j = 0; j < 4; j++) w[j] = tile[tc4 + j][tr_];
  *(u16x4*)&dst[(size_t)(c0 + tr_) * R + r0 + tc4] = w;
}

// ---------------- small fp32 GEMM (64-col weight GEMMs), optional relu(A) -----
template<bool RELU>
__global__ __launch_bounds__(256)
void gemm_small_k(const float* __restrict__ A, const float* __restrict__ B,
                  float* __restrict__ C, int M, int Nc, int K,
                  int ldA, int ldB, int ldC)
{
  __shared__ float As[16][68];
  __shared__ float Bs[16][68];
  int tid = threadIdx.x;
  int tx = tid & 15, ty = tid >> 4;
  int row0 = blockIdx.y * 64, col0 = blockIdx.x * 64;
  float acc[4][4] = {};

  for (int k0 = 0; k0 < K; k0 += 16) {
    {
      int m = tid >> 2, kk = (tid & 3) << 2;
      const float* ap = A + (size_t)(row0 + m) * ldA + k0 + kk;
      float4 v = *(const float4*)ap;
      if (RELU) {
        v.x = fmaxf(v.x, 0.f); v.y = fmaxf(v.y, 0.f);
        v.z = fmaxf(v.z, 0.f); v.w = fmaxf(v.w, 0.f);
      }
      As[kk + 0][m] = v.x; As[kk + 1][m] = v.y; As[kk + 2][m] = v.z; As[kk + 3][m] = v.w;
    }
    {
      int kk = tid >> 4, c = (tid & 15) << 2;
      const float* bp = B + (size_t)(k0 + kk) * ldB + col0 + c;
      #pragma unroll
      for (int i = 0; i < 4; i++)
        Bs[kk][c + i] = (col0 + c + i < Nc) ? bp[i] : 0.f;
    }
    __syncthreads();
    #pragma unroll
    for (int kk = 0; kk < 16; kk++) {
      float4 a4 = *(const float4*)&As[kk][ty << 2];
      float4 b4 = *(const float4*)&Bs[kk][tx << 2];
      float av[4] = {a4.x, a4.y, a4.z, a4.w};
      float bv[4] = {b4.x, b4.y, b4.z, b4.w};
      #pragma unroll
      for (int i = 0; i < 4; i++)
        #pragma unroll
        for (int j = 0; j < 4; j++)
          acc[i][j] = fmaf(av[i], bv[j], acc[i][j]);
    }
    __syncthreads();
  }
  #pragma unroll
  for (int i = 0; i < 4; i++) {
    int r = row0 + (ty << 2) + i;
    #pragma unroll
    for (int j = 0; j < 4; j++) {
      int c = col0 + (tx << 2) + j;
      if (c < Nc) C[(size_t)r * ldC + c] = acc[i][j];
    }
  }
}

// ---------------- fused Sinkhorn passes ----------------
__global__ __launch_bounds__(256)
void sink_k(float* __restrict__ P, unsigned short* __restrict__ Pb,
            const float* __restrict__ cs_in, float* __restrict__ cs_out,
            float* __restrict__ rs, int mode)
{
  int tid = threadIdx.x;
  int r0 = blockIdx.x * 8;
  float csl[16] = {};
  float cdiv[16];
  if (mode != 0) {
    #pragma unroll
    for (int t = 0; t < 4; t++) {
      float4 c4 = ((const float4*)cs_in)[tid + t * 256];
      cdiv[4 * t + 0] = 1.f / (4096.f * c4.x);
      cdiv[4 * t + 1] = 1.f / (4096.f * c4.y);
      cdiv[4 * t + 2] = 1.f / (4096.f * c4.z);
      cdiv[4 * t + 3] = 1.f / (4096.f * c4.w);
    }
  }
  for (int rr = 0; rr < 8; rr++) {
    int row = r0 + rr;
    float4* prow = (float4*)(P + (size_t)row * 4096);
    float4 r[4];
    #pragma unroll
    for (int t = 0; t < 4; t++) r[t] = prow[tid + t * 256];

    if (mode == 0) {
      float m = -3.4e38f;
      #pragma unroll
      for (int t = 0; t < 4; t++)
        m = fmaxf(m, fmaxf(fmaxf(r[t].x, r[t].y), fmaxf(r[t].z, r[t].w)));
      m = blk_red<true>(m);
      float s = 0.f;
      #pragma unroll
      for (int t = 0; t < 4; t++) {
        r[t].x = expf(r[t].x - m); r[t].y = expf(r[t].y - m);
        r[t].z = expf(r[t].z - m); r[t].w = expf(r[t].w - m);
        s += r[t].x + r[t].y + r[t].z + r[t].w;
      }
      s = blk_red<false>(s);
      float f = 1.f / (s * 4096.f);
      #pragma unroll
      for (int t = 0; t < 4; t++) {
        r[t].x *= f; r[t].y *= f; r[t].z *= f; r[t].w *= f;
        prow[tid + t * 256] = r[t];
        csl[4 * t + 0] += r[t].x; csl[4 * t + 1] += r[t].y;
        csl[4 * t + 2] += r[t].z; csl[4 * t + 3] += r[t].w;
      }
    } else {
      float s = 0.f;
      #pragma unroll
      for (int t = 0; t < 4; t++) {
        r[t].x *= cdiv[4 * t + 0]; r[t].y *= cdiv[4 * t + 1];
        r[t].z *= cdiv[4 * t + 2]; r[t].w *= cdiv[4 * t + 3];
        s += r[t].x + r[t].y + r[t].z + r[t].w;
      }
      s = blk_red<false>(s);
      if (mode == 1) {
        float f = 1.f / (4096.f * s);
        #pragma unroll
        for (int t = 0; t < 4; t++) {
          r[t].x *= f; r[t].y *= f; r[t].z *= f; r[t].w *= f;
          prow[tid + t * 256] = r[t];
          csl[4 * t + 0] += r[t].x; csl[4 * t + 1] += r[t].y;
          csl[4 * t + 2] += r[t].z; csl[4 * t + 3] += r[t].w;
        }
      } else {
        if (tid == 0) rs[row] = s;
        #pragma unroll
        for (int t = 0; t < 4; t++) {
          prow[tid + t * 256] = r[t];
          u16x4 w;
          w[0] = f2bf(r[t].x); w[1] = f2bf(r[t].y);
          w[2] = f2bf(r[t].z); w[3] = f2bf(r[t].w);
          *(u16x4*)&Pb[(size_t)row * 4096 + 4 * (tid + t * 256)] = w;
          csl[4 * t + 0] += r[t].x; csl[4 * t + 1] += r[t].y;
          csl[4 * t + 2] += r[t].z; csl[4 * t + 3] += r[t].w;
        }
      }
    }
  }
  #pragma unroll
  for (int t = 0; t < 4; t++) {
    int j = 4 * (tid + t * 256);
    atomicAdd(&cs_out[j + 0], csl[4 * t + 0]);
    atomicAdd(&cs_out[j + 1], csl[4 * t + 1]);
    atomicAdd(&cs_out[j + 2], csl[4 * t + 2]);
    atomicAdd(&cs_out[j + 3], csl[4 * t + 3]);
  }
}

__global__ void gather_k(float* __restrict__ XP, const int* __restrict__ perm)
{
  int gid = blockIdx.x * 256 + threadIdx.x;
  int i = gid >> 6, j = gid & 63;
  XP[(size_t)i * 128 + 64 + j] = XP[(size_t)perm[i] * 128 + j];
}

__global__ void readout_k(const float* __restrict__ vs2, const float* __restrict__ mrs,
                          float* __restrict__ g2)
{
  int q = blockIdx.x, j = threadIdx.x;
  float v = vs2[(size_t)q * 64 + j] / mrs[q >> 1];
  float p = v * v;
  #pragma unroll
  for (int s = 1; s < 64; s <<= 1) p += __shfl_xor(p, s, 64);
  float nrm = sqrtf(p);
  v = v / fmaxf(nrm, 1e-12f);
  g2[(size_t)q * 64 + j] = 1.f / (1.f + expf(-v));
}

__device__ __forceinline__ float bce_term(float x, float y) {
  return fmaxf(x, 0.f) - x * y + log1pf(expf(-fabsf(x)));
}

__global__ void disc_k(const float* __restrict__ G2, const float* __restrict__ W2,
                       const float* __restrict__ lab, const float* __restrict__ bptr,
                       float* __restrict__ acc)
{
  int i = blockIdx.x, j = threadIdx.x;
  float gj  = G2[(size_t)(2 * i) * 64 + j];
  float gaj = G2[(size_t)(2 * i + 1) * 64 + j];
  float hw  = W2[(size_t)(2 * i) * 64 + j];
  float haw = W2[(size_t)(2 * i + 1) * 64 + j];
  float s1 = hw * gj, s2 = haw * gj, s1a = haw * gaj, s2a = hw * gaj;
  #pragma unroll
  for (int s = 1; s < 64; s <<= 1) {
    s1  += __shfl_xor(s1, s, 64);
    s2  += __shfl_xor(s2, s, 64);
    s1a += __shfl_xor(s1a, s, 64);
    s2a += __shfl_xor(s2a, s, 64);
  }
  if (j == 0) {
    float b = bptr[0];
    float y0 = lab[i * 2 + 0], y1 = lab[i * 2 + 1];
    float t = bce_term(s1 + b, y0) + bce_term(s2 + b, y1)
            + bce_term(s1a + b, y0) + bce_term(s2a + b, y1);
    atomicAdd(&acc[SL], t);
  }
}

__global__ __launch_bounds__(256)
void finalize_k(const float* __restrict__ acc, const float* __restrict__ cs,
                float* __restrict__ out)
{
  int tid = threadIdx.x;
  float invm2 = 1.f / (float)kN;
  float t = 0.f;
  for (int j = tid; j < kN; j += 256) {
    float q = cs[j];
    t += q * (logf(q) - invm2);
  }
  t = blk_red<false>(t);
  if (tid == 0) {
    float kld_pq = t * invm2;
    float kld_pp = invm2 * (logf(invm2) - invm2);
    out[0] = acc[SL] / (2.f * (float)kN);
    out[1] = acc[FEAT] / ((float)kN * (float)kIN);
    out[2] = acc[ALN];
    out[3] = (acc[FXA] + acc[FXB]) / ((float)kN * (float)kIN);
    out[4] = sqrtf(acc[SM1]) / (float)kN + sqrtf(acc[SM2]) / (float)kN;
    out[5] = (kld_pq - kld_pp) * (float)kN;
    out[6] = -acc[SPS];
  }
}

extern "C" void kernel_launch(void* const* d_in, const int* in_sizes, int n_in,
                              void* d_out, int out_size, void* d_ws, size_t ws_size,
                              hipStream_t stream)
{
  (void)in_sizes; (void)n_in; (void)out_size; (void)ws_size;
  const float* feat  = (const float*)d_in[0];
  const float* adjs  = (const float*)d_in[1];
  const float* gmask = (const float*)d_in[2];
  const float* labs  = (const float*)d_in[3];
  const float* dists = (const float*)d_in[4];
  const int*   perms = (const int*)d_in[5];
  const float* encW  = (const float*)d_in[6];
  const float* decW  = (const float*)d_in[7];
  const float* MsW   = (const float*)d_in[8];
  const float* discW = (const float*)d_in[9];
  const float* discb = (const float*)d_in[10];
  float* out = (float*)d_out;

  const size_t SZNN = (size_t)kN * kN;

  char* cur = (char*)d_ws;
  auto alloc = [&](size_t bytes) {
    char* p = cur;
    cur += (bytes + 255) & ~(size_t)255;
    return p;
  };
  float* P            = (float*)alloc(SZNN * 4);          // fp32 P; later Tb
  unsigned short* Pb  = (unsigned short*)alloc(SZNN * 2);
  unsigned short* PbT = (unsigned short*)alloc(SZNN * 2);
  unsigned short* Db  = (unsigned short*)alloc(SZNN * 2); // D bf16; also ftb2
  unsigned short* ajb = (unsigned short*)alloc(SZNN * 2); // adj/msk bf16; later ftb
  unsigned short* xb0 = (unsigned short*)alloc((size_t)kN * kINp * 2);
  unsigned short* xb1 = (unsigned short*)alloc((size_t)kN * kINp * 2);
  unsigned short* dWtb= (unsigned short*)alloc((size_t)kINp * kLAT * 2);
  unsigned short* ahb = (unsigned short*)alloc((size_t)kN * kLAT * 2);
  unsigned short* encWtp = (unsigned short*)alloc((size_t)128 * kINp * 2);
  unsigned short* XPt = (unsigned short*)alloc((size_t)128 * kN * 2);
  unsigned short* hbTp= (unsigned short*)alloc((size_t)128 * kN * 2);
  unsigned short* HRt = (unsigned short*)alloc((size_t)128 * kN * 2);
  unsigned short* smb = (unsigned short*)alloc((size_t)kN * kLAT * 2);
  unsigned short* tmb = (unsigned short*)alloc((size_t)kN * kLAT * 2);
  unsigned short* h0b = (unsigned short*)alloc((size_t)kN * kLAT * 2);
  unsigned short* h1b = (unsigned short*)alloc((size_t)kN * kLAT * 2);
  float* XP  = (float*)alloc((size_t)kN * 128 * 4);
  float* HH0 = (float*)alloc((size_t)kN * 128 * 4);
  float* HH1 = (float*)alloc((size_t)kN * 128 * 4);
  float* VS  = (float*)alloc((size_t)kN * 128 * 4);
  float* G2  = (float*)alloc((size_t)kN * 128 * 4);
  float* W2  = (float*)alloc((size_t)kN * 128 * 4);
  float* SM_ = (float*)alloc((size_t)kN * kLAT * 4);
  float* TM_ = (float*)alloc((size_t)kN * kLAT * 4);
  float* ah  = (float*)alloc((size_t)kN * kLAT * 4);
  float* sns = (float*)alloc(kN * 4);
  float* snt = (float*)alloc(kN * 4);
  float* rs  = (float*)alloc(kN * 4);
  float* cs  = (float*)alloc(kN * 4);
  float* csA = (float*)alloc(kN * 4);
  float* csB = (float*)alloc(kN * 4);
  float* mrs = (float*)alloc(kN * 4);
  float* acc = (float*)alloc(NSLOT * 4);

  unsigned short* Tb  = (unsigned short*)P;   // alias: fp32 P dead before Tb written
  unsigned short* ftb = ajb;                  // alias: adj/msk bf16 dead after slices
  unsigned short* ftb2= Db;                   // alias: Db unused until maintain

  hipMemsetAsync(acc, 0, NSLOT * sizeof(float), stream);

  // ---------------- per-slice losses ----------------
  for (int k = 0; k < 2; k++) {
    const float* x    = feat  + (size_t)k * kN * kIN;
    const float* adj  = adjs  + (size_t)k * SZNN;
    const float* msk  = gmask + (size_t)k * SZNN;
    const float* lab  = labs  + (size_t)k * kN * 2;
    const int*   perm = perms + (size_t)k * kN;
    const float* eW   = encW  + (size_t)k * kIN * kLAT;
    const float* dW   = decW  + (size_t)k * kLAT * kIN;
    float* HHk = (k == 0) ? HH0 : HH1;
    unsigned short* xbk = (k == 0) ? xb0 : xb1;

    cvt_pad_k<<<6144, 256, 0, stream>>>(x, xbk);
    hipMemsetAsync(encWtp, 0, (size_t)128 * kINp * 2, stream);
    tr_k<false><<<dim3(2, (kIN + 31) / 32), 256, 0, stream>>>(eW, encWtp, kIN, kLAT, kLAT, kINp);
    hipMemsetAsync(XP, 0, (size_t)kN * 128 * 4, stream);
    ns_mfma_k<<<512, 256, 0, stream>>>(xbk, encWtp, XP, kLAT, kINp, kINp / 16, 128);
    gather_k<<<kN * 64 / 256, 256, 0, stream>>>(XP, perm);
    tr_k<false><<<dim3(4, 128), 256, 0, stream>>>(XP, XPt, kN, 128, 128, kN);
    cvt_k<<<(int)(SZNN / 8 / 256), 256, 0, stream>>>(adj, ajb, (int)(SZNN / 8), 1.f);
    hipMemsetAsync(HHk, 0, (size_t)kN * 128 * 4, stream);
    ns_mfma_k<<<512, 256, 0, stream>>>(ajb, XPt, HHk, 128, kN, kN / 16, 128);
    hipMemsetAsync(hbTp, 0, (size_t)128 * kN * 2, stream);
    tr_k<false><<<dim3(2, 128), 256, 0, stream>>>(HHk, hbTp, kN, kLAT, 128, kN);
    hipMemsetAsync(ah, 0, (size_t)kN * kLAT * 4, stream);
    ns_mfma_k<<<512, 256, 0, stream>>>(ajb, hbTp, ah, kLAT, kN, kN / 16, kLAT);
    cvt_k<<<128, 256, 0, stream>>>(ah, ahb, kN * kLAT / 8, 1.f);
    tr_k<false><<<dim3(kINp / 32, 2), 256, 0, stream>>>(dW, dWtb, kLAT, kIN, kIN, kLAT);
    bt_mfma_k<2, 1><<<(kINp / 128) * 32, 256, 0, stream>>>(
        ahb, dWtb, nullptr, nullptr, xbk, nullptr, nullptr, &acc[FEAT],
        kINp / 128, kIN, kLAT, kINp, 0);
    tr_k<true><<<dim3(4, 128), 256, 0, stream>>>(HHk, HRt, kN, 128, 128, kN);
    hipMemsetAsync(mrs, 0, kN * 4, stream);
    cvt_rs_k<<<(int)(SZNN / 8 / 256), 256, 0, stream>>>(msk, ajb, mrs);
    hipMemsetAsync(VS, 0, (size_t)kN * 128 * 4, stream);
    ns_mfma_k<<<512, 256, 0, stream>>>(ajb, HRt, VS, 128, kN, kN / 16, 128);
    readout_k<<<2 * kN, 64, 0, stream>>>(VS, mrs, G2);
    gemm_small_k<true><<<dim3(1, 128), 256, 0, stream>>>(HHk, discW, W2, 2 * kN, kLAT,
                                                         kLAT, kLAT, kLAT, kLAT);
    disc_k<<<kN, 64, 0, stream>>>(G2, W2, lab, discb, acc);
  }

  // ---------------- alignment losses ----------------
  const float* D0 = dists;
  const float* D1 = dists + SZNN;

  gemm_small_k<false><<<dim3(1, 64), 256, 0, stream>>>(HH0, MsW, SM_, kN, kLAT, kLAT,
                                                       128, kLAT, kLAT);
  gemm_small_k<false><<<dim3(1, 64), 256, 0, stream>>>(HH1, MsW, TM_, kN, kLAT, kLAT,
                                                       128, kLAT, kLAT);
  cvt_k<<<128, 256, 0, stream>>>(SM_, smb, kN * kLAT / 8, 0.125f);
  cvt_k<<<128, 256, 0, stream>>>(TM_, tmb, kN * kLAT / 8, 1.f);
  // P = srcM @ tgtM^T / 8  (128-tile MFMA, fp32 store)
  bt_mfma_k<1, 0><<<1024, 256, 0, stream>>>(smb, tmb, nullptr, P, nullptr, nullptr, nullptr,
                                            nullptr, 32, kN, kLAT, 0, 0);

  // fused sinkhorn: softmax + 3 iters + final marginals + bf16 P, 4 passes
  hipMemsetAsync(csA, 0, kN * 4, stream);
  sink_k<<<512, 256, 0, stream>>>(P, nullptr, nullptr, csA, nullptr, 0);
  hipMemsetAsync(csB, 0, kN * 4, stream);
  sink_k<<<512, 256, 0, stream>>>(P, nullptr, csA, csB, nullptr, 1);
  hipMemsetAsync(csA, 0, kN * 4, stream);
  sink_k<<<512, 256, 0, stream>>>(P, nullptr, csB, csA, nullptr, 1);
  hipMemsetAsync(cs, 0, kN * 4, stream);
  sink_k<<<512, 256, 0, stream>>>(P, Pb, csA, cs, rs, 2);

  // PbT = bf16(P^T) — last read of fp32 P
  tr_k<false><<<dim3(kN / 32, kN / 32), 256, 0, stream>>>(P, PbT, kN, kN, kN, kN);

  // align + sparsity: h0@h1^T (EPI3); fused h-bf16 + sqnorms
  cvtsq_k<<<1024, 256, 0, stream>>>(HH0, h0b, sns);
  cvtsq_k<<<1024, 256, 0, stream>>>(HH1, h1b, snt);
  bt_mfma_k<3, 1><<<1024, 256, 0, stream>>>(h0b, h1b, nullptr, nullptr, Pb, sns, snt, acc,
                                            32, kN, kLAT, kN, 0);

  // loss_align_fix: merged FXA+FXB, flat 1536 blocks (= 3 full rounds, 0 tail)
  tr_bf_k<<<dim3(kINp / 32, kN / 32), 256, 0, stream>>>(xb1, ftb, kN, kINp);
  tr_bf_k<<<dim3(kINp / 32, kN / 32), 256, 0, stream>>>(xb0, ftb2, kN, kINp);
  bt2f_mfma_k<<<2 * (kINp / 128) * 32, 256, 0, stream>>>(
      Pb,  ftb,  xb0, rs, &acc[FXA],
      PbT, ftb2, xb1, cs, &acc[FXB],
      kINp / 128, kIN, kN, kINp, (kINp / 128) * 32);

  // loss_maintain 1: Tb = (P@D1)/rs (dense) ; SM1 = sum((D0 - (Tb@P^T)/rs)^2) sym
  cvt_k<<<(int)(SZNN / 8 / 256), 256, 0, stream>>>(D1, Db, (int)(SZNN / 8), 1.f);
  bt_mfma_k<0, 0><<<1024, 256, 0, stream>>>(Pb, Db, Tb, nullptr, nullptr, rs, nullptr,
                                            nullptr, 32, kN, kN, 0, 0);
  bt_mfma_k<2, 0><<<528, 256, 0, stream>>>(Tb, Pb, nullptr, nullptr, D0, nullptr, rs,
                                           &acc[SM1], 32, kN, kN, kN, 1);
  // loss_maintain 2: Tb = (P^T@D0)/cs (dense) ; SM2 = sum((D1 - (Tb@P)/cs)^2) sym
  cvt_k<<<(int)(SZNN / 8 / 256), 256, 0, stream>>>(D0, Db, (int)(SZNN / 8), 1.f);
  bt_mfma_k<0, 0><<<1024, 256, 0, stream>>>(PbT, Db, Tb, nullptr, nullptr, cs, nullptr,
                                            nullptr, 32, kN, kN, 0, 0);
  bt_mfma_k<2, 0><<<528, 256, 0, stream>>>(Tb, PbT, nullptr, nullptr, D1, nullptr, cs,
                                           &acc[SM2], 32, kN, kN, kN, 1);

  finalize_k<<<1, 256, 0, stream>>>(acc, cs, out);
}